// Round 3
// baseline (205.712 us; speedup 1.0000x reference)
//
#include <hip/hip_runtime.h>
#include <math.h>

// loss = mean_b[ 0.5*nrmse(o1,t1) + 0.25*nrmse(o2,t2) + 0.25*nrmse(o3,t3) ]
// B=4096 rows, N=2048 fp32/row. Memory-latency-bound; fix = max MLP per wave.
constexpr int N_ELEM = 2048;
constexpr int BATCH  = 4096;
constexpr int BLOCK  = 256;                   // 4 waves/block
constexpr int TASKS  = 3 * BATCH;             // 12288 (pair,row) tasks
constexpr int GRID1  = TASKS / (BLOCK / 64);  // 3072 blocks: one wave per task

// Stage 1: one wave per row. Load the ENTIRE o-row and t-row into registers
// (16 x global_load_dwordx4 per lane, all issued before first use -> 16
// outstanding loads/lane), then subtract/reduce as vmcnt drains.
__global__ __launch_bounds__(BLOCK)
void wnrmse_stage1(const float* __restrict__ o1, const float* __restrict__ t1,
                   const float* __restrict__ o2, const float* __restrict__ t2,
                   const float* __restrict__ o3, const float* __restrict__ t3,
                   float* __restrict__ partial)
{
    const int tid  = threadIdx.x;
    const int wave = tid >> 6;
    const int lane = tid & 63;
    const int task = blockIdx.x * (BLOCK / 64) + wave;   // 0..12287

    const int pair = task >> 12;           // wave-uniform
    const int row  = task & (BATCH - 1);

    const float* o;
    const float* t;
    float w;
    if (pair == 0)      { o = o1; t = t1; w = 0.50f; }
    else if (pair == 1) { o = o2; t = t2; w = 0.25f; }
    else                { o = o3; t = t3; w = 0.25f; }

    const float4* o4 = (const float4*)(o + (size_t)row * N_ELEM);
    const float4* t4 = (const float4*)(t + (size_t)row * N_ELEM);

    // Issue all 16 loads before any consumption: 64 data VGPRs live.
    float4 ov[8], tv[8];
#pragma unroll
    for (int j = 0; j < 8; ++j) ov[j] = o4[lane + j * 64];
#pragma unroll
    for (int j = 0; j < 8; ++j) tv[j] = t4[lane + j * 64];

    // 4 independent accumulator chains for ssd; max/min trees.
    float s0 = 0.f, s1 = 0.f, s2 = 0.f, s3 = 0.f;
    float tmax = -INFINITY, tmin = INFINITY;
#pragma unroll
    for (int j = 0; j < 8; ++j) {
        float d0 = ov[j].x - tv[j].x;
        float d1 = ov[j].y - tv[j].y;
        float d2 = ov[j].z - tv[j].z;
        float d3 = ov[j].w - tv[j].w;
        s0 += d0 * d0;
        s1 += d1 * d1;
        s2 += d2 * d2;
        s3 += d3 * d3;
        tmax = fmaxf(tmax, fmaxf(fmaxf(tv[j].x, tv[j].y), fmaxf(tv[j].z, tv[j].w)));
        tmin = fminf(tmin, fminf(fminf(tv[j].x, tv[j].y), fminf(tv[j].z, tv[j].w)));
    }
    float ssd = (s0 + s1) + (s2 + s3);

    // Wave-64 butterfly reduce.
#pragma unroll
    for (int off = 32; off > 0; off >>= 1) {
        ssd  += __shfl_xor(ssd, off, 64);
        tmax  = fmaxf(tmax, __shfl_xor(tmax, off, 64));
        tmin  = fminf(tmin, __shfl_xor(tmin, off, 64));
    }

    __shared__ float s_part[BLOCK / 64];
    if (lane == 0) {
        float rmse = sqrtf(ssd * (1.0f / (float)N_ELEM));
        s_part[wave] = w * rmse / (tmax - tmin);
    }
    __syncthreads();
    if (tid == 0) {
        partial[blockIdx.x] = s_part[0] + s_part[1] + s_part[2] + s_part[3];
    }
}

// Stage 2: one block reduces GRID1 partials and writes the scalar.
__global__ __launch_bounds__(BLOCK)
void wnrmse_stage2(const float* __restrict__ partial, float* __restrict__ out)
{
    const int tid = threadIdx.x;
    float s = 0.0f;
    for (int i = tid; i < GRID1; i += BLOCK) s += partial[i];   // 12 iters

#pragma unroll
    for (int off = 32; off > 0; off >>= 1) s += __shfl_xor(s, off, 64);

    __shared__ float s_part[BLOCK / 64];
    const int wave = tid >> 6;
    const int lane = tid & 63;
    if (lane == 0) s_part[wave] = s;
    __syncthreads();
    if (tid == 0) {
        float tot = s_part[0] + s_part[1] + s_part[2] + s_part[3];
        out[0] = tot * (1.0f / (float)BATCH);
    }
}

extern "C" void kernel_launch(void* const* d_in, const int* in_sizes, int n_in,
                              void* d_out, int out_size, void* d_ws, size_t ws_size,
                              hipStream_t stream) {
    const float* o1 = (const float*)d_in[0];
    const float* t1 = (const float*)d_in[1];
    const float* o2 = (const float*)d_in[2];
    const float* t2 = (const float*)d_in[3];
    const float* o3 = (const float*)d_in[4];
    const float* t3 = (const float*)d_in[5];
    float* out     = (float*)d_out;
    float* partial = (float*)d_ws;    // GRID1 floats = 12 KiB, fully overwritten

    wnrmse_stage1<<<GRID1, BLOCK, 0, stream>>>(o1, t1, o2, t2, o3, t3, partial);
    wnrmse_stage2<<<1, BLOCK, 0, stream>>>(partial, out);
}

// Round 4
// 205.243 us; speedup vs baseline: 1.0023x; 1.0023x over previous
//
#include <hip/hip_runtime.h>
#include <math.h>

// loss = mean_b[ 0.5*nrmse(o1,t1) + 0.25*nrmse(o2,t2) + 0.25*nrmse(o3,t3) ]
// B=4096 rows, N=2048 fp32/row, 192 MiB streamed. Latency-bound so far:
// compiler sinks staged loads (VGPR=36). This version pins a register
// double-buffer pipeline with sched_barrier(0) so each wave keeps 16
// global_load_dwordx4 (128 cache lines) in flight ~all the time.
constexpr int N_ELEM = 2048;
constexpr int BATCH  = 4096;
constexpr int BLOCK  = 256;                    // 4 waves/block
constexpr int GRID1  = 1024;                   // 4 blocks/CU
constexpr int WAVES1 = GRID1 * (BLOCK / 64);   // 4096 waves
constexpr int TASKS  = 3 * BATCH;              // 12288 rows
constexpr int RPW    = TASKS / WAVES1;         // 3 rows per wave

__device__ __forceinline__ void issue_row(const float4* __restrict__ o4,
                                          const float4* __restrict__ t4,
                                          int lane, float4 ov[8], float4 tv[8])
{
#pragma unroll
    for (int j = 0; j < 8; ++j) ov[j] = o4[lane + j * 64];
#pragma unroll
    for (int j = 0; j < 8; ++j) tv[j] = t4[lane + j * 64];
}

__device__ __forceinline__ void consume_row(const float4 ov[8], const float4 tv[8],
                                            float& ssd, float& tmax, float& tmin)
{
    float s0 = 0.f, s1 = 0.f, s2 = 0.f, s3 = 0.f;
    float mx = -INFINITY, mn = INFINITY;
#pragma unroll
    for (int j = 0; j < 8; ++j) {
        float d0 = ov[j].x - tv[j].x;
        float d1 = ov[j].y - tv[j].y;
        float d2 = ov[j].z - tv[j].z;
        float d3 = ov[j].w - tv[j].w;
        s0 += d0 * d0;  s1 += d1 * d1;  s2 += d2 * d2;  s3 += d3 * d3;
        mx = fmaxf(mx, fmaxf(fmaxf(tv[j].x, tv[j].y), fmaxf(tv[j].z, tv[j].w)));
        mn = fminf(mn, fminf(fminf(tv[j].x, tv[j].y), fminf(tv[j].z, tv[j].w)));
    }
    ssd = (s0 + s1) + (s2 + s3);
    tmax = mx;
    tmin = mn;
}

__global__ __launch_bounds__(BLOCK, 1)
void wnrmse_stage1(const float* __restrict__ o1, const float* __restrict__ t1,
                   const float* __restrict__ o2, const float* __restrict__ t2,
                   const float* __restrict__ o3, const float* __restrict__ t3,
                   float* __restrict__ partial)
{
    const int tid  = threadIdx.x;
    const int wave = tid >> 6;
    const int lane = tid & 63;
    const int gw   = blockIdx.x * (BLOCK / 64) + wave;   // 0..4095
    const int base = gw * RPW;                            // 3 contiguous tasks

    const float* const os[3] = { o1, o2, o3 };
    const float* const ts[3] = { t1, t2, t3 };
    const float wgt[3] = { 0.50f, 0.25f, 0.25f };

    // Per-task pointers (wave-uniform pair/row per task).
    const float4* o4p[RPW];
    const float4* t4p[RPW];
    float wv[RPW];
#pragma unroll
    for (int k = 0; k < RPW; ++k) {
        const int task = base + k;
        const int pair = task >> 12;
        const int row  = task & (BATCH - 1);
        o4p[k] = (const float4*)(os[pair]) + (size_t)row * (N_ELEM / 4);
        t4p[k] = (const float4*)(ts[pair]) + (size_t)row * (N_ELEM / 4);
        wv[k]  = wgt[pair];
    }

    float4 A_o[8], A_t[8], B_o[8], B_t[8];
    float ssd[RPW], tmax[RPW], tmin[RPW];

    // Pinned pipeline: loads(0) | loads(1) | consume(0) | loads(2) |
    // consume(1) | consume(2). sched_barrier(0) stops the scheduler from
    // sinking loads into the consume bodies (which is what produced the
    // 36-VGPR, 2-outstanding-load code in R2/R3).
    issue_row(o4p[0], t4p[0], lane, A_o, A_t);
    __builtin_amdgcn_sched_barrier(0);
    issue_row(o4p[1], t4p[1], lane, B_o, B_t);
    __builtin_amdgcn_sched_barrier(0);
    consume_row(A_o, A_t, ssd[0], tmax[0], tmin[0]);
    __builtin_amdgcn_sched_barrier(0);
    issue_row(o4p[2], t4p[2], lane, A_o, A_t);
    __builtin_amdgcn_sched_barrier(0);
    consume_row(B_o, B_t, ssd[1], tmax[1], tmin[1]);
    __builtin_amdgcn_sched_barrier(0);
    consume_row(A_o, A_t, ssd[2], tmax[2], tmin[2]);

    // Cross-lane reduce all three rows at the end (chains interleave -> ILP).
#pragma unroll
    for (int off = 32; off > 0; off >>= 1) {
#pragma unroll
        for (int k = 0; k < RPW; ++k) {
            ssd[k]  += __shfl_xor(ssd[k], off, 64);
            tmax[k]  = fmaxf(tmax[k], __shfl_xor(tmax[k], off, 64));
            tmin[k]  = fminf(tmin[k], __shfl_xor(tmin[k], off, 64));
        }
    }

    __shared__ float s_part[BLOCK / 64];
    if (lane == 0) {
        float local = 0.f;
#pragma unroll
        for (int k = 0; k < RPW; ++k) {
            float rmse = sqrtf(ssd[k] * (1.0f / (float)N_ELEM));
            local += wv[k] * rmse / (tmax[k] - tmin[k]);
        }
        s_part[wave] = local;
    }
    __syncthreads();
    if (tid == 0) {
        partial[blockIdx.x] = s_part[0] + s_part[1] + s_part[2] + s_part[3];
    }
}

// Stage 2: one block reduces GRID1 partials and writes the scalar.
__global__ __launch_bounds__(BLOCK)
void wnrmse_stage2(const float* __restrict__ partial, float* __restrict__ out)
{
    const int tid = threadIdx.x;
    float s = 0.0f;
    for (int i = tid; i < GRID1; i += BLOCK) s += partial[i];   // 4 iters

#pragma unroll
    for (int off = 32; off > 0; off >>= 1) s += __shfl_xor(s, off, 64);

    __shared__ float s_part[BLOCK / 64];
    const int wave = tid >> 6;
    const int lane = tid & 63;
    if (lane == 0) s_part[wave] = s;
    __syncthreads();
    if (tid == 0) {
        float tot = s_part[0] + s_part[1] + s_part[2] + s_part[3];
        out[0] = tot * (1.0f / (float)BATCH);
    }
}

extern "C" void kernel_launch(void* const* d_in, const int* in_sizes, int n_in,
                              void* d_out, int out_size, void* d_ws, size_t ws_size,
                              hipStream_t stream) {
    const float* o1 = (const float*)d_in[0];
    const float* t1 = (const float*)d_in[1];
    const float* o2 = (const float*)d_in[2];
    const float* t2 = (const float*)d_in[3];
    const float* o3 = (const float*)d_in[4];
    const float* t3 = (const float*)d_in[5];
    float* out     = (float*)d_out;
    float* partial = (float*)d_ws;    // GRID1 floats = 4 KiB, fully overwritten

    wnrmse_stage1<<<GRID1, BLOCK, 0, stream>>>(o1, t1, o2, t2, o3, t3, partial);
    wnrmse_stage2<<<1, BLOCK, 0, stream>>>(partial, out);
}